// Round 3
// baseline (79.372 us; speedup 1.0000x reference)
//
#include <hip/hip_runtime.h>

// LinearAttention: B=4, H=8, L=4096, D=64, fp32 in/out.
// out = elu1(Q) @ KV / (elu1(Q)·Ksum + eps),  KV = elu1(K)^T @ V  (L-scalings cancel).
//
// K1 : 1024 blocks (32 heads x 32 chunks), LDS-FREE streaming outer product.
//      Lane (dq,vq) owns an 8d x 8v patch; K/V fragments loaded directly from
//      global (8-way multicast within wave -> L1). Cross-wave reduce in LDS,
//      partial written to private ws slot.
// K1r: 160 blocks reduce 32 partials/head -> final KV + Ksum.
// K2 : 512 blocks (32 heads x 16 tiles of 256 rows). KV+Ksum in LDS (reused),
//      Q streamed via registers (fmap in-reg), den fused into main loop.
// Main-loop FMAs packed as v_pk_fma_f32 via __builtin_elementwise_fma.

#define LSEQ   4096
#define DDIM   64
#define NHEAD  32
#define K1CH   32
#define K1ROWS (LSEQ / K1CH)          // 128 rows per K1 block
#define WSPH   (DDIM * DDIM + DDIM)   // 4160 floats per partial / head
#define WSPH4  (WSPH / 4)             // 1040 float4

typedef float f2 __attribute__((ext_vector_type(2)));

__device__ __forceinline__ float fmap(float x) {
    // elu(x) + 1 = x+1 if x>0 else exp(x)
    return x > 0.0f ? (x + 1.0f) : __expf(x);
}
__device__ __forceinline__ f2 pkfma(f2 a, f2 b, f2 c) {
    return __builtin_elementwise_fma(a, b, c);   // -> v_pk_fma_f32
}

// ---------------- Kernel 1: partial KV[64][64] + Ksum[64] per (head,chunk) ----
__global__ __launch_bounds__(256) void la_kv_kernel(
    const float* __restrict__ Kg, const float* __restrict__ Vg,
    float* __restrict__ ws)
{
    __shared__ float red[WSPH];

    const int t    = threadIdx.x;
    const int wave = t >> 6;
    const int lane = t & 63;
    const int dq   = lane >> 3;
    const int vq   = lane & 7;

    const int bh    = blockIdx.x / K1CH;
    const int chunk = blockIdx.x % K1CH;
    const size_t base = (size_t)bh * LSEQ * DDIM + (size_t)chunk * K1ROWS * DDIM
                      + (size_t)wave * 32 * DDIM;   // 32 rows per wave
    const float* Kp = Kg + base;
    const float* Vp = Vg + base;

    f2 acc[8][4];          // 8 d-rows x 8 v-cols (as 4 f2)
    float ksum[8];
#pragma unroll
    for (int i = 0; i < 8; ++i) {
        ksum[i] = 0.0f;
#pragma unroll
        for (int j = 0; j < 4; ++j) acc[i][j] = (f2)(0.0f);
    }

#pragma unroll 1
    for (int g = 0; g < 4; ++g) {                 // 4 groups of 8 rows
        const float* kR = Kp + g * 8 * DDIM;
        const float* vR = Vp + g * 8 * DDIM;
#pragma unroll
        for (int r = 0; r < 8; ++r) {
            const float4 ka = *(const float4*)(kR + r * DDIM + dq * 8);
            const float4 kb = *(const float4*)(kR + r * DDIM + dq * 8 + 4);
            const float4 va = *(const float4*)(vR + r * DDIM + vq * 4);
            const float4 vb = *(const float4*)(vR + r * DDIM + 32 + vq * 4);
            const float kk[8] = {fmap(ka.x), fmap(ka.y), fmap(ka.z), fmap(ka.w),
                                 fmap(kb.x), fmap(kb.y), fmap(kb.z), fmap(kb.w)};
            const f2 vv[4] = {{va.x, va.y}, {va.z, va.w}, {vb.x, vb.y}, {vb.z, vb.w}};
#pragma unroll
            for (int i = 0; i < 8; ++i) {
                ksum[i] += kk[i];
                const f2 ki = {kk[i], kk[i]};
#pragma unroll
                for (int j = 0; j < 4; ++j)
                    acc[i][j] = pkfma(ki, vv[j], acc[i][j]);
            }
        }
    }

    // sequential cross-wave reduce into LDS (wave w adds on its turn)
    for (int w = 0; w < 4; ++w) {
        __syncthreads();
        if (wave == w) {
#pragma unroll
            for (int i = 0; i < 8; ++i) {
                const int d = dq * 8 + i;
                float* p = red + d * DDIM + vq * 4;
                float4 lo = make_float4(acc[i][0].x, acc[i][0].y, acc[i][1].x, acc[i][1].y);
                float4 hi = make_float4(acc[i][2].x, acc[i][2].y, acc[i][3].x, acc[i][3].y);
                if (w != 0) {
                    const float4 plo = *(const float4*)p;
                    const float4 phi = *(const float4*)(p + 32);
                    lo.x += plo.x; lo.y += plo.y; lo.z += plo.z; lo.w += plo.w;
                    hi.x += phi.x; hi.y += phi.y; hi.z += phi.z; hi.w += phi.w;
                }
                *(float4*)p = lo;
                *(float4*)(p + 32) = hi;
            }
            if (vq == 0) {
                float* p = red + DDIM * DDIM + dq * 8;
                float4 s0 = make_float4(ksum[0], ksum[1], ksum[2], ksum[3]);
                float4 s1 = make_float4(ksum[4], ksum[5], ksum[6], ksum[7]);
                if (w != 0) {
                    const float4 p0 = *(const float4*)p;
                    const float4 p1 = *(const float4*)(p + 4);
                    s0.x += p0.x; s0.y += p0.y; s0.z += p0.z; s0.w += p0.w;
                    s1.x += p1.x; s1.y += p1.y; s1.z += p1.z; s1.w += p1.w;
                }
                *(float4*)p = s0;
                *(float4*)(p + 4) = s1;
            }
        }
    }
    __syncthreads();

    // coalesced store of the block's partial into its PRIVATE slot
    float4* dst = (float4*)(ws + (size_t)blockIdx.x * WSPH);
    const float4* src = (const float4*)red;
    for (int i = t; i < WSPH4; i += 256)
        dst[i] = src[i];
}

// ---------------- Kernel 1r: reduce 32 partials per head -> final KV+Ksum ----
__global__ __launch_bounds__(256) void la_reduce_kernel(
    const float* __restrict__ ws, float* __restrict__ kvout)
{
    const int h   = blockIdx.x / 5;
    const int seg = blockIdx.x % 5;
    const int t   = threadIdx.x;
    if (t >= 208) return;
    const int i4 = seg * 208 + t;

    const float4* base = (const float4*)(ws + (size_t)h * K1CH * WSPH) + i4;
    float4 acc = make_float4(0.f, 0.f, 0.f, 0.f);
#pragma unroll 8
    for (int p = 0; p < K1CH; ++p) {
        const float4 x = base[(size_t)p * WSPH4];
        acc.x += x.x; acc.y += x.y; acc.z += x.z; acc.w += x.w;
    }
    ((float4*)(kvout + (size_t)h * WSPH))[i4] = acc;
}

// ---------------- Kernel 2: out = (Qf @ KV) / (Qf·Ksum + eps) -----------------
// grid = NHEAD*16, 256 threads; block = 256 rows. Lane (rg = t>>3, vq = t&7)
// owns rows [rg*8, rg*8+8) and cols {vq*4..+3, 32+vq*4..+3}.
__global__ __launch_bounds__(256) void la_out_kernel(
    const float* __restrict__ Qg, const float* __restrict__ kvin,
    float* __restrict__ out)
{
    __shared__ float kvlds[DDIM * DDIM];
    __shared__ float ksl[DDIM];

    const int t    = threadIdx.x;
    const int bh   = blockIdx.x >> 4;
    const int tile = blockIdx.x & 15;
    const size_t base = (size_t)bh * LSEQ * DDIM + (size_t)tile * 256 * DDIM;

    // stage KV (1024 float4) + Ksum (16 float4) once
    const float4* wsrc = (const float4*)(kvin + (size_t)bh * WSPH);
    for (int i = t; i < WSPH4; i += 256) {
        const float4 x = wsrc[i];
        if (i < 1024) ((float4*)kvlds)[i] = x;
        else          ((float4*)ksl)[i - 1024] = x;
    }
    __syncthreads();

    const int rg = t >> 3;
    const int vq = t & 7;
    const float* qrow = Qg + base + (size_t)rg * 8 * DDIM;
    float*       orow = out + base + (size_t)rg * 8 * DDIM;

    f2 acc[8][4];           // 8 rows x 8 cols
    float den[8];
#pragma unroll
    for (int r = 0; r < 8; ++r) {
        den[r] = 0.0f;
#pragma unroll
        for (int j = 0; j < 4; ++j) acc[r][j] = (f2)(0.0f);
    }

#pragma unroll 1
    for (int d4 = 0; d4 < 16; ++d4) {
        f2 kL[4][2], kH[4][2];
#pragma unroll
        for (int i = 0; i < 4; ++i) {
            const float4 a = *(const float4*)(kvlds + (d4 * 4 + i) * DDIM + vq * 4);
            const float4 b = *(const float4*)(kvlds + (d4 * 4 + i) * DDIM + 32 + vq * 4);
            kL[i][0] = (f2){a.x, a.y}; kL[i][1] = (f2){a.z, a.w};
            kH[i][0] = (f2){b.x, b.y}; kH[i][1] = (f2){b.z, b.w};
        }
        const float4 ks4 = *(const float4*)(ksl + d4 * 4);
#pragma unroll
        for (int r = 0; r < 8; ++r) {
            float4 q = *(const float4*)(qrow + r * DDIM + d4 * 4);
            q.x = fmap(q.x); q.y = fmap(q.y); q.z = fmap(q.z); q.w = fmap(q.w);
            den[r] += q.x * ks4.x + q.y * ks4.y + q.z * ks4.z + q.w * ks4.w;
            const float qa[4] = {q.x, q.y, q.z, q.w};
#pragma unroll
            for (int i = 0; i < 4; ++i) {
                const f2 qb = {qa[i], qa[i]};
                acc[r][0] = pkfma(qb, kL[i][0], acc[r][0]);
                acc[r][1] = pkfma(qb, kL[i][1], acc[r][1]);
                acc[r][2] = pkfma(qb, kH[i][0], acc[r][2]);
                acc[r][3] = pkfma(qb, kH[i][1], acc[r][3]);
            }
        }
    }

#pragma unroll
    for (int r = 0; r < 8; ++r) {
        const float z = 1.0f / (den[r] + 1e-6f);
        float4 lo = make_float4(acc[r][0].x * z, acc[r][0].y * z,
                                acc[r][1].x * z, acc[r][1].y * z);
        float4 hi = make_float4(acc[r][2].x * z, acc[r][2].y * z,
                                acc[r][3].x * z, acc[r][3].y * z);
        *(float4*)(orow + r * DDIM + vq * 4) = lo;
        *(float4*)(orow + r * DDIM + 32 + vq * 4) = hi;
    }
}

extern "C" void kernel_launch(void* const* d_in, const int* in_sizes, int n_in,
                              void* d_out, int out_size, void* d_ws, size_t ws_size,
                              hipStream_t stream) {
    const float* q = (const float*)d_in[0];
    const float* k = (const float*)d_in[1];
    const float* v = (const float*)d_in[2];
    float* o  = (float*)d_out;
    float* ws = (float*)d_ws;
    // ws layout: [0, 1024*WSPH) partials; then 32*WSPH reduced KV.
    float* kvfinal = ws + (size_t)NHEAD * K1CH * WSPH;

    hipLaunchKernelGGL(la_kv_kernel, dim3(NHEAD * K1CH), dim3(256), 0, stream,
                       k, v, ws);
    hipLaunchKernelGGL(la_reduce_kernel, dim3(NHEAD * 5), dim3(256), 0, stream,
                       ws, kvfinal);
    hipLaunchKernelGGL(la_out_kernel, dim3(NHEAD * 16), dim3(256), 0, stream,
                       q, kvfinal, o);
}